// Round 16
// baseline (109.612 us; speedup 1.0000x reference)
//
#include <hip/hip_runtime.h>

static constexpr int CH   = 128;   // CHANNELS
static constexpr int KPAD = 192;   // Atile row length (bf16) -> 384B rows

typedef __attribute__((ext_vector_type(8))) short bf16x8;
typedef __attribute__((ext_vector_type(4))) float f32x4;

__device__ inline unsigned short f2bf(float x) {
    unsigned int u = __float_as_uint(x);
    unsigned int r = (u + 0x7fffu + ((u >> 16) & 1u)) >> 16;  // RNE
    return (unsigned short)r;
}
__device__ inline unsigned int pack2bf(float a, float b) {
    return (unsigned int)f2bf(a) | ((unsigned int)f2bf(b) << 16);
}

// meta layout (u32): [0..15] hist, [16..31] cursor, [32..48] bucket bases.
// ---------------------------------------------------------------------------
// Fused prep kernel.
//  blocks 0..19     : Wf fragment-linear weight layout (proven r10)
//  blocks 20..801   : out[e] = 0.0f zero-fill (atomic accumulation base)
//  blocks 802..1313 : 16-bucket histogram, bucket = slice(src)*4 + slice(dst),
//                     slice(n) = umulhi(n, M32); is64 detect inlined.
// ---------------------------------------------------------------------------
__global__ __launch_bounds__(256) void prep_all(
    const float* __restrict__ w1, const float* __restrict__ b1,
    unsigned short* __restrict__ Wf, const unsigned int* __restrict__ idxw,
    float* __restrict__ out, unsigned int* __restrict__ meta,
    int E, unsigned int M32) {
    const int t = threadIdx.x;
    if (blockIdx.x < 20) {
        const int gid = blockIdx.x * 256 + t;  // 0..5119
        const int lane = gid & 63;
        const int seg  = gid >> 6;
        const int m    = seg & 3;
        const int ks   = (seg >> 2) % 5;
        const int w    = seg / 20;
        const int c    = w * 64 + m * 16 + (lane & 15);
        const int k0   = ks * 32 + (lane >> 4) * 8;
        const bool isQ = c >= 128;
        const int cc   = c & 127;
        const float sgn = isQ ? 1.f : -1.f;
        unsigned int outw[4];
#pragma unroll
        for (int h = 0; h < 4; ++h) {
            float v[2];
#pragma unroll
            for (int j = 0; j < 2; ++j) {
                const int k = k0 + 2 * h + j;
                float x;
                if (k < 128)       x = isQ ? w1[(size_t)(128 + k) * CH + cc]
                                           : w1[(size_t)k * CH + cc];
                else if (k == 128) x = sgn * w1[(size_t)(2 * CH) * CH + cc];
                else if (k == 129) x = sgn * w1[(size_t)(2 * CH + 1) * CH + cc];
                else if (k == 130) x = isQ ? b1[cc] : 0.f;
                else               x = 0.f;
                v[j] = x;
            }
            outw[h] = pack2bf(v[0], v[1]);
        }
        *(uint4*)&Wf[(size_t)gid * 8] =
            make_uint4(outw[0], outw[1], outw[2], outw[3]);
        return;
    }
    if (blockIdx.x < 802) {
        const int base = (blockIdx.x - 20) * 1024 + t * 4;
        if (base + 3 < E) {
            *(float4*)&out[base] = make_float4(0.f, 0.f, 0.f, 0.f);
        } else {
            for (int i = base; i < E; ++i) out[i] = 0.f;
        }
        return;
    }
    // ---- histogram ----
    __shared__ unsigned int lh[16];
    unsigned nz = 0;
    const int lane = t & 63;
    for (int i = lane; i < 128; i += 64) nz |= idxw[2 * i + 1];
    const int is64 = (__ballot(nz != 0u) == 0ULL) ? 1 : 0;
    if (t < 16) lh[t] = 0;
    __syncthreads();
    const int stride = 512 * 256;
    for (int e = (blockIdx.x - 802) * 256 + t; e < E; e += stride) {
        const unsigned s = is64 ? idxw[2 * e] : idxw[e];
        const unsigned d = is64 ? idxw[2 * (E + e)] : idxw[E + e];
        atomicAdd(&lh[__umulhi(s, M32) * 4 + __umulhi(d, M32)], 1u);
    }
    __syncthreads();
    if (t < 16 && lh[t]) atomicAdd(&meta[t], lh[t]);
}

__global__ void scan16(unsigned int* __restrict__ meta, int E) {
    if (threadIdx.x == 0) {
        unsigned int acc = 0;
        for (int b = 0; b < 16; ++b) {
            meta[32 + b] = acc;   // bucket base
            meta[16 + b] = acc;   // cursor
            acc += meta[b];
        }
        meta[48] = (unsigned int)E;
    }
}

// ---------------------------------------------------------------------------
// Scatter: sorted[pos] = { src | dst<<16, edge_id } bucketed by
// (src-slice, dst-slice). Two-phase per chunk: LDS rank -> one global
// atomic per bucket per block -> write.
// ---------------------------------------------------------------------------
__global__ __launch_bounds__(256) void scatter16(
    const unsigned int* __restrict__ idxw, int E, unsigned int M32,
    unsigned int* __restrict__ meta, uint2* __restrict__ sorted) {
    __shared__ unsigned int lh[16], gb[16];
    const int t = threadIdx.x;
    unsigned nz = 0;
    const int lane = t & 63;
    for (int i = lane; i < 128; i += 64) nz |= idxw[2 * i + 1];
    const int is64 = (__ballot(nz != 0u) == 0ULL) ? 1 : 0;
    for (int cb = blockIdx.x * 1024; cb < E; cb += gridDim.x * 1024) {
        if (t < 16) lh[t] = 0;
        __syncthreads();
        unsigned sv[4], dv[4], bb[4], rk[4];
        bool ok[4];
#pragma unroll
        for (int j = 0; j < 4; ++j) {
            const int e = cb + j * 256 + t;
            ok[j] = e < E;
            if (ok[j]) {
                sv[j] = is64 ? idxw[2 * e] : idxw[e];
                dv[j] = is64 ? idxw[2 * (E + e)] : idxw[E + e];
                bb[j] = __umulhi(sv[j], M32) * 4 + __umulhi(dv[j], M32);
                rk[j] = atomicAdd(&lh[bb[j]], 1u);
            }
        }
        __syncthreads();
        if (t < 16) gb[t] = lh[t] ? atomicAdd(&meta[16 + t], lh[t]) : 0u;
        __syncthreads();
#pragma unroll
        for (int j = 0; j < 4; ++j) {
            if (ok[j]) {
                const int e = cb + j * 256 + t;
                sorted[gb[bb[j]] + rk[j]] =
                    make_uint2(sv[j] | (dv[j] << 16), (unsigned)e);
            }
        }
        __syncthreads();
    }
}

// ---------------------------------------------------------------------------
// Node stage (r14-proven): 32 nodes x 256 cols, swapped-operand MFMA, K=160
// (coords+bias folded), Wf fragment-linear loads, swizzled LDS out-tile ->
// coalesced 16B stores. Output: 4 half-buffers [N][64] bf16 (128B rows).
// ---------------------------------------------------------------------------
__global__ __launch_bounds__(256) void node_mfma7(
    const float* __restrict__ tokens, const float* __restrict__ coords,
    const unsigned short* __restrict__ Wf, unsigned short* __restrict__ Plo,
    unsigned short* __restrict__ Phi, unsigned short* __restrict__ Qlo,
    unsigned short* __restrict__ Qhi, int N) {
    __shared__ unsigned short Atile[32 * KPAD];   // 12 KB, XOR-swizzled rows
    __shared__ unsigned short Otile[32 * 256];    // 16 KB, XOR-swizzled rows

    const int t    = threadIdx.x;
    const int l    = t & 63;
    const int wid  = t >> 6;
    const int n0   = blockIdx.x * 32;
    const int bl   = l & 15;
    const int bh   = l >> 4;

#pragma unroll
    for (int it = 0; it < 2; ++it) {
        const int idx  = it * 256 + t;
        const int node = idx >> 4;
        const int cq   = idx & 15;
        float4 v0 = make_float4(0.f, 0.f, 0.f, 0.f);
        float4 v1 = v0;
        if (n0 + node < N) {
            const float* src = &tokens[(size_t)(n0 + node) * CH + cq * 8];
            v0 = *(const float4*)src;
            v1 = *(const float4*)(src + 4);
        }
        uint4 u;
        u.x = pack2bf(v0.x, v0.y);
        u.y = pack2bf(v0.z, v0.w);
        u.z = pack2bf(v1.x, v1.y);
        u.w = pack2bf(v1.z, v1.w);
        const int byte = node * 384 + ((cq * 16) ^ ((node & 7) << 4));
        *(uint4*)((char*)Atile + byte) = u;
    }
    {
        const int node = t >> 3;
        const int ce   = t & 7;
        uint4 u = make_uint4(0u, 0u, 0u, 0u);
        if (ce == 0 && n0 + node < N) {
            const float cx = coords[2 * (n0 + node)];
            const float cy = coords[2 * (n0 + node) + 1];
            u.x = pack2bf(cx, cy);
            u.y = pack2bf(1.f, 0.f);
        }
        const int byte = node * 384 + (((16 + ce) * 16) ^ ((node & 7) << 4));
        *(uint4*)((char*)Atile + byte) = u;
    }
    __syncthreads();

    f32x4 acc[4][2];
#pragma unroll
    for (int m = 0; m < 4; ++m)
#pragma unroll
        for (int n = 0; n < 2; ++n) acc[m][n] = (f32x4){0.f, 0.f, 0.f, 0.f};

#pragma unroll
    for (int ks = 0; ks < 5; ++ks) {
        bf16x8 wfrag[4], tfrag[2];
#pragma unroll
        for (int m = 0; m < 4; ++m)
            wfrag[m] = *(const bf16x8*)&Wf[(size_t)(((wid * 5 + ks) * 4 + m) * 64
                                                    + l) * 8];
#pragma unroll
        for (int n = 0; n < 2; ++n) {
            const int row  = n * 16 + bl;
            const int byte = row * 384 + ((ks * 64 + bh * 16) ^ ((row & 7) << 4));
            tfrag[n] = *(const bf16x8*)((const char*)Atile + byte);
        }
#pragma unroll
        for (int m = 0; m < 4; ++m)
#pragma unroll
            for (int n = 0; n < 2; ++n)
                acc[m][n] = __builtin_amdgcn_mfma_f32_16x16x32_bf16(
                    wfrag[m], tfrag[n], acc[m][n], 0, 0, 0);
    }

#pragma unroll
    for (int m = 0; m < 4; ++m) {
        const int col = wid * 64 + m * 16 + bh * 4;   // 0..255
#pragma unroll
        for (int n = 0; n < 2; ++n) {
            const int node = n * 16 + bl;             // local 0..31
            uint2 val;
            val.x = pack2bf(acc[m][n][0], acc[m][n][1]);
            val.y = pack2bf(acc[m][n][2], acc[m][n][3]);
            const int byte = node * 512 + ((col * 2) ^ ((node & 7) << 4));
            *(uint2*)((char*)Otile + byte) = val;
        }
    }
    __syncthreads();

#pragma unroll
    for (int it = 0; it < 2; ++it) {
        const int idx  = it * 256 + t;   // 0..511
        const int node = idx >> 4;       // local 0..31
        const int seg  = idx & 15;       // 16 segs x 32B (16 cols)
        const int gn   = n0 + node;
        if (gn < N) {
            unsigned short* dst = (seg < 4) ? Plo : (seg < 8) ? Phi
                                  : (seg < 12) ? Qlo : Qhi;
            const int colq = (seg & 3) * 16;
#pragma unroll
            for (int h = 0; h < 2; ++h) {
                const int byte = node * 512 +
                                 ((seg * 32 + h * 16) ^ ((node & 7) << 4));
                const uint4 v = *(const uint4*)((const char*)Otile + byte);
                *(uint4*)&dst[(size_t)gn * 64 + colq + h * 8] = v;
            }
        }
    }
}

// ---------------------------------------------------------------------------
// Sorted edge kernel. half = blockIdx&1 (= XCD parity under %8 round-robin),
// picks channel half. All blocks sweep buckets 0..15 in order; each block
// takes a contiguous chunk of the bucket -> concurrent blocks on an XCD share
// one bucket's 3.2 MB (P-slice + Q-slice) working set. 8-lane group owns 4
// edges; full 128B row per gather (8 lanes x 16B). Two deterministic
// atomicAdds per edge onto a zero base; bias folded into half 1.
// ---------------------------------------------------------------------------
__global__ __launch_bounds__(256) void edge_sorted2(
    const uint2* __restrict__ sorted, const unsigned int* __restrict__ meta,
    const unsigned short* __restrict__ Plo, const unsigned short* __restrict__ Phi,
    const unsigned short* __restrict__ Qlo, const unsigned short* __restrict__ Qhi,
    const float* __restrict__ w2, const float* __restrict__ b2,
    float* __restrict__ out) {
    const int half = blockIdx.x & 1;
    const int id   = blockIdx.x >> 1;
    const int nid  = gridDim.x >> 1;
    const int t  = threadIdx.x;
    const int gl = t & 7;
    const int g  = t >> 3;   // group 0..31
    const float4 wa = *(const float4*)&w2[half * 64 + gl * 8];
    const float4 wb = *(const float4*)&w2[half * 64 + gl * 8 + 4];
    const float bias = half ? b2[0] : 0.f;
    const char* P = (const char*)(half ? Phi : Plo);
    const char* Q = (const char*)(half ? Qhi : Qlo);

    for (int b = 0; b < 16; ++b) {
        const unsigned r0 = meta[32 + b];
        const unsigned r1 = meta[32 + b + 1];
        if (r1 <= r0) continue;
        const unsigned len = r1 - r0;
        const unsigned per = (len + nid - 1) / (unsigned)nid;
        const unsigned cb0 = r0 + (unsigned)id * per;
        if (cb0 >= r1) continue;
        const unsigned cb1 = (cb0 + per < r1) ? (cb0 + per) : r1;

        for (unsigned be = cb0 + g * 4; be < cb1; be += 128) {
            const unsigned me = be + (gl & 3);
            const uint2 ent = sorted[me < cb1 ? me : cb1 - 1];
            unsigned soff[4], doff[4];
#pragma unroll
            for (int j = 0; j < 4; ++j) {
                const unsigned sx = __shfl(ent.x, j, 8);
                soff[j] = (sx & 0xffffu) << 7;
                doff[j] = (sx >> 16) << 7;
            }
            uint4 pv[4], qv[4];
#pragma unroll
            for (int j = 0; j < 4; ++j)
                pv[j] = *(const uint4*)(P + soff[j] + 16 * gl);
#pragma unroll
            for (int j = 0; j < 4; ++j)
                qv[j] = *(const uint4*)(Q + doff[j] + 16 * gl);

            float part[4];
#pragma unroll
            for (int j = 0; j < 4; ++j) {
                const float wv[8] = {wa.x, wa.y, wa.z, wa.w,
                                     wb.x, wb.y, wb.z, wb.w};
                const unsigned pw[4] = {pv[j].x, pv[j].y, pv[j].z, pv[j].w};
                const unsigned qw[4] = {qv[j].x, qv[j].y, qv[j].z, qv[j].w};
                float acc = 0.f;
#pragma unroll
                for (int i = 0; i < 4; ++i) {
                    const float plo = __uint_as_float(pw[i] << 16);
                    const float phi = __uint_as_float(pw[i] & 0xffff0000u);
                    const float qlo = __uint_as_float(qw[i] << 16);
                    const float qhi = __uint_as_float(qw[i] & 0xffff0000u);
                    acc = fmaf(fmaxf(plo + qlo, 0.f), wv[2 * i], acc);
                    acc = fmaf(fmaxf(phi + qhi, 0.f), wv[2 * i + 1], acc);
                }
                part[j] = acc;
            }

            // width-8 butterfly; lane gl<4 ends with edge (be+gl)'s sum
            float t0 = part[0] + __shfl_xor(part[0], 1);
            float t1 = part[1] + __shfl_xor(part[1], 1);
            float t2 = part[2] + __shfl_xor(part[2], 1);
            float t3 = part[3] + __shfl_xor(part[3], 1);
            float a0 = (gl & 1) ? t1 : t0;
            float a1 = (gl & 1) ? t3 : t2;
            a0 += __shfl_xor(a0, 2);
            a1 += __shfl_xor(a1, 2);
            float c = (gl & 2) ? a1 : a0;
            c += __shfl_xor(c, 4);

            if (gl < 4 && be + gl < cb1) atomicAdd(&out[ent.y], c + bias);
        }
    }
}

extern "C" void kernel_launch(void* const* d_in, const int* in_sizes, int n_in,
                              void* d_out, int out_size, void* d_ws,
                              size_t ws_size, hipStream_t stream) {
    const float* tokens = (const float*)d_in[0];
    const float* coords = (const float*)d_in[1];
    const unsigned int* idxw = (const unsigned int*)d_in[2];
    const float* w1 = (const float*)d_in[3];
    const float* b1 = (const float*)d_in[4];
    const float* w2 = (const float*)d_in[5];
    const float* b2 = (const float*)d_in[6];
    float* out = (float*)d_out;

    const int N = in_sizes[0] / CH;       // 50000
    const int E = (int)(in_sizes[2] / 2); // 800000
    const unsigned slice = (unsigned)((N + 3) / 4);
    const unsigned M32 = (unsigned)((0x100000000ULL + slice - 1) / slice);

    unsigned short* Plo = (unsigned short*)d_ws;   // [N][64] each
    unsigned short* Phi = Plo + (size_t)N * 64;
    unsigned short* Qlo = Phi + (size_t)N * 64;
    unsigned short* Qhi = Qlo + (size_t)N * 64;
    uint2* sorted = (uint2*)(Qhi + (size_t)N * 64);        // E entries
    unsigned short* Wf = (unsigned short*)(sorted + ((E + 1) & ~1));
    unsigned int* meta = (unsigned int*)(Wf + 5120 * 8);   // 64 u32

    hipMemsetAsync(meta, 0, 64 * sizeof(unsigned int), stream);

    prep_all<<<1314, 256, 0, stream>>>(w1, b1, Wf, idxw, out, meta, E, M32);
    scan16<<<1, 64, 0, stream>>>(meta, E);
    scatter16<<<1024, 256, 0, stream>>>(idxw, E, M32, meta, sorted);

    node_mfma7<<<(N + 31) / 32, 256, 0, stream>>>(tokens, coords, Wf,
                                                  Plo, Phi, Qlo, Qhi, N);

    edge_sorted2<<<1024, 256, 0, stream>>>(sorted, meta, Plo, Phi, Qlo, Qhi,
                                           w2, b2, out);
}

// Round 17
// 67.059 us; speedup vs baseline: 1.6345x; 1.6345x over previous
//
#include <hip/hip_runtime.h>

static constexpr int CH   = 128;   // CHANNELS
static constexpr int KPAD = 192;   // Atile row length (bf16) -> 384B rows

typedef __attribute__((ext_vector_type(8))) short bf16x8;
typedef __attribute__((ext_vector_type(4))) float f32x4;

__device__ inline unsigned short f2bf(float x) {
    unsigned int u = __float_as_uint(x);
    unsigned int r = (u + 0x7fffu + ((u >> 16) & 1u)) >> 16;  // RNE
    return (unsigned short)r;
}
__device__ inline unsigned int pack2bf(float a, float b) {
    return (unsigned int)f2bf(a) | ((unsigned int)f2bf(b) << 16);
}

// ---------------------------------------------------------------------------
// Wf fragment-linear weight layout (proven r10). 20 blocks, ~2us.
// ---------------------------------------------------------------------------
__global__ __launch_bounds__(256) void wf_prep(const float* __restrict__ w1,
                                               const float* __restrict__ b1,
                                               unsigned short* __restrict__ Wf) {
    const int gid = blockIdx.x * 256 + threadIdx.x;  // 0..5119
    const int lane = gid & 63;
    const int seg  = gid >> 6;
    const int m    = seg & 3;
    const int ks   = (seg >> 2) % 5;
    const int w    = seg / 20;
    const int c    = w * 64 + m * 16 + (lane & 15);
    const int k0   = ks * 32 + (lane >> 4) * 8;
    const bool isQ = c >= 128;
    const int cc   = c & 127;
    const float sgn = isQ ? 1.f : -1.f;
    unsigned int outw[4];
#pragma unroll
    for (int h = 0; h < 4; ++h) {
        float v[2];
#pragma unroll
        for (int j = 0; j < 2; ++j) {
            const int k = k0 + 2 * h + j;
            float x;
            if (k < 128)       x = isQ ? w1[(size_t)(128 + k) * CH + cc]
                                       : w1[(size_t)k * CH + cc];
            else if (k == 128) x = sgn * w1[(size_t)(2 * CH) * CH + cc];
            else if (k == 129) x = sgn * w1[(size_t)(2 * CH + 1) * CH + cc];
            else if (k == 130) x = isQ ? b1[cc] : 0.f;
            else               x = 0.f;
            v[j] = x;
        }
        outw[h] = pack2bf(v[0], v[1]);
    }
    *(uint4*)&Wf[(size_t)gid * 8] = make_uint4(outw[0], outw[1], outw[2], outw[3]);
}

// ---------------------------------------------------------------------------
// Node stage + fused independent prep.
//  blocks [0, NB)           : r14-proven MFMA node work (reads Wf)
//  blocks [NB, NB+782)      : out[e] = 0.0f zero-fill (atomic base)
//  blocks [NB+782, +512)    : idxp[e] = src | dst<<16 (is64 detect inlined)
// ---------------------------------------------------------------------------
__global__ __launch_bounds__(256) void node_fused(
    const float* __restrict__ tokens, const float* __restrict__ coords,
    const unsigned short* __restrict__ Wf, unsigned short* __restrict__ Plo,
    unsigned short* __restrict__ Phi, unsigned short* __restrict__ Qlo,
    unsigned short* __restrict__ Qhi, int N, int NB,
    const unsigned int* __restrict__ idxw, unsigned int* __restrict__ idxp,
    float* __restrict__ out, int E) {
    __shared__ unsigned short Atile[32 * KPAD];   // 12 KB, XOR-swizzled rows
    __shared__ unsigned short Otile[32 * 256];    // 16 KB, XOR-swizzled rows

    const int t = threadIdx.x;

    if (blockIdx.x >= NB) {
        const int xb = blockIdx.x - NB;
        if (xb < 782) {
            const int base = xb * 1024 + t * 4;
            if (base + 3 < E) {
                *(float4*)&out[base] = make_float4(0.f, 0.f, 0.f, 0.f);
            } else {
                for (int i = base; i < E; ++i) out[i] = 0.f;
            }
        } else {
            unsigned nz = 0;
            const int lane = t & 63;
            for (int i = lane; i < 128; i += 64) nz |= idxw[2 * i + 1];
            const int is64 = (__ballot(nz != 0u) == 0ULL) ? 1 : 0;
            const int stride = 512 * 256;
            for (int e = (xb - 782) * 256 + t; e < E; e += stride) {
                const unsigned s = is64 ? idxw[2 * e] : idxw[e];
                const unsigned d = is64 ? idxw[2 * (E + e)] : idxw[E + e];
                idxp[e] = s | (d << 16);
            }
        }
        return;
    }

    const int l    = t & 63;
    const int wid  = t >> 6;
    const int n0   = blockIdx.x * 32;
    const int bl   = l & 15;
    const int bh   = l >> 4;

    // token chunks: 32 nodes x 16 chunks of 16B
#pragma unroll
    for (int it = 0; it < 2; ++it) {
        const int idx  = it * 256 + t;
        const int node = idx >> 4;
        const int cq   = idx & 15;
        float4 v0 = make_float4(0.f, 0.f, 0.f, 0.f);
        float4 v1 = v0;
        if (n0 + node < N) {
            const float* src = &tokens[(size_t)(n0 + node) * CH + cq * 8];
            v0 = *(const float4*)src;
            v1 = *(const float4*)(src + 4);
        }
        uint4 u;
        u.x = pack2bf(v0.x, v0.y);
        u.y = pack2bf(v0.z, v0.w);
        u.z = pack2bf(v1.x, v1.y);
        u.w = pack2bf(v1.z, v1.w);
        const int byte = node * 384 + ((cq * 16) ^ ((node & 7) << 4));
        *(uint4*)((char*)Atile + byte) = u;
    }
    // ext chunks: k=128..191 -> (cx, cy, 1, 0, ...)
    {
        const int node = t >> 3;
        const int ce   = t & 7;
        uint4 u = make_uint4(0u, 0u, 0u, 0u);
        if (ce == 0 && n0 + node < N) {
            const float cx = coords[2 * (n0 + node)];
            const float cy = coords[2 * (n0 + node) + 1];
            u.x = pack2bf(cx, cy);
            u.y = pack2bf(1.f, 0.f);
        }
        const int byte = node * 384 + (((16 + ce) * 16) ^ ((node & 7) << 4));
        *(uint4*)((char*)Atile + byte) = u;
    }
    __syncthreads();

    f32x4 acc[4][2];
#pragma unroll
    for (int m = 0; m < 4; ++m)
#pragma unroll
        for (int n = 0; n < 2; ++n) acc[m][n] = (f32x4){0.f, 0.f, 0.f, 0.f};

#pragma unroll
    for (int ks = 0; ks < 5; ++ks) {
        bf16x8 wfrag[4], tfrag[2];
#pragma unroll
        for (int m = 0; m < 4; ++m)
            wfrag[m] = *(const bf16x8*)&Wf[(size_t)(((wid * 5 + ks) * 4 + m) * 64
                                                    + l) * 8];
#pragma unroll
        for (int n = 0; n < 2; ++n) {
            const int row  = n * 16 + bl;
            const int byte = row * 384 + ((ks * 64 + bh * 16) ^ ((row & 7) << 4));
            tfrag[n] = *(const bf16x8*)((const char*)Atile + byte);
        }
#pragma unroll
        for (int m = 0; m < 4; ++m)
#pragma unroll
            for (int n = 0; n < 2; ++n)
                acc[m][n] = __builtin_amdgcn_mfma_f32_16x16x32_bf16(
                    wfrag[m], tfrag[n], acc[m][n], 0, 0, 0);
    }

    // ---- epilogue: fragments -> swizzled Otile (node-major rows) ----
#pragma unroll
    for (int m = 0; m < 4; ++m) {
        const int col = wid * 64 + m * 16 + bh * 4;   // 0..255
#pragma unroll
        for (int n = 0; n < 2; ++n) {
            const int node = n * 16 + bl;             // local 0..31
            uint2 val;
            val.x = pack2bf(acc[m][n][0], acc[m][n][1]);
            val.y = pack2bf(acc[m][n][2], acc[m][n][3]);
            const int byte = node * 512 + ((col * 2) ^ ((node & 7) << 4));
            *(uint2*)((char*)Otile + byte) = val;
        }
    }
    __syncthreads();

    // ---- coalesced store: 32B per thread-iter, seg selects buffer ----
#pragma unroll
    for (int it = 0; it < 2; ++it) {
        const int idx  = it * 256 + t;   // 0..511
        const int node = idx >> 4;       // local 0..31
        const int seg  = idx & 15;       // 16 segs x 32B (16 cols)
        const int gn   = n0 + node;
        if (gn < N) {
            unsigned short* dst = (seg < 4) ? Plo : (seg < 8) ? Phi
                                  : (seg < 12) ? Qlo : Qhi;
            const int colq = (seg & 3) * 16;
#pragma unroll
            for (int h = 0; h < 2; ++h) {
                const int byte = node * 512 +
                                 ((seg * 32 + h * 16) ^ ((node & 7) << 4));
                const uint4 v = *(const uint4*)((const char*)Otile + byte);
                *(uint4*)&dst[(size_t)gn * 64 + colq + h * 8] = v;
            }
        }
    }
}

// ---------------------------------------------------------------------------
// Fused edge kernel (r15-proven): half = blockIdx&1 (= XCD parity under %8
// round-robin) picks the channel half -> per-XCD working set 12.8 MB; both
// halves run concurrently. idxp is 4B/edge (src|dst<<16). Two deterministic
// atomicAdds per edge onto the zero base; bias folded into half 1.
// ---------------------------------------------------------------------------
__global__ __launch_bounds__(256) void edge_fused(
    const unsigned int* __restrict__ idxp,
    const unsigned short* __restrict__ Plo, const unsigned short* __restrict__ Phi,
    const unsigned short* __restrict__ Qlo, const unsigned short* __restrict__ Qhi,
    const float* __restrict__ w2, const float* __restrict__ b2,
    float* __restrict__ out, long long E) {
    const int half = blockIdx.x & 1;
    const int t  = threadIdx.x;
    const int gl = t & 7;
    const long long nq = (E + 3) >> 2;                       // edge quads
    const long long pb = blockIdx.x >> 1;
    const long long g0 = pb * 32 + (t >> 3);
    const long long ng = (long long)(gridDim.x >> 1) * 32;
    const float4 wa = *(const float4*)&w2[half * 64 + gl * 8];
    const float4 wb = *(const float4*)&w2[half * 64 + gl * 8 + 4];
    const float bias = half ? b2[0] : 0.f;
    const char* P = (const char*)(half ? Phi : Plo);
    const char* Q = (const char*)(half ? Qhi : Qlo);

    for (long long q = g0; q < nq; q += ng) {
        const long long e0 = q << 2;
        const unsigned iv = __builtin_nontemporal_load(&idxp[e0 + (gl & 3)]);
        unsigned soff[4], doff[4];
#pragma unroll
        for (int j = 0; j < 4; ++j) {
            const unsigned sx = __shfl(iv, j, 8);
            soff[j] = (sx & 0xffffu) << 7;
            doff[j] = (sx >> 16) << 7;
        }
        uint4 pv[4], qv[4];
#pragma unroll
        for (int j = 0; j < 4; ++j)
            pv[j] = *(const uint4*)(P + soff[j] + 16 * gl);
#pragma unroll
        for (int j = 0; j < 4; ++j)
            qv[j] = *(const uint4*)(Q + doff[j] + 16 * gl);

        float part[4];
#pragma unroll
        for (int j = 0; j < 4; ++j) {
            const float wv[8] = {wa.x, wa.y, wa.z, wa.w, wb.x, wb.y, wb.z, wb.w};
            const unsigned pw[4] = {pv[j].x, pv[j].y, pv[j].z, pv[j].w};
            const unsigned qw[4] = {qv[j].x, qv[j].y, qv[j].z, qv[j].w};
            float acc = 0.f;
#pragma unroll
            for (int i = 0; i < 4; ++i) {
                const float plo = __uint_as_float(pw[i] << 16);
                const float phi = __uint_as_float(pw[i] & 0xffff0000u);
                const float qlo = __uint_as_float(qw[i] << 16);
                const float qhi = __uint_as_float(qw[i] & 0xffff0000u);
                acc = fmaf(fmaxf(plo + qlo, 0.f), wv[2 * i], acc);
                acc = fmaf(fmaxf(phi + qhi, 0.f), wv[2 * i + 1], acc);
            }
            part[j] = acc;
        }

        // width-8 butterfly with packing; lane gl<4 ends with edge gl's sum
        float t0 = part[0] + __shfl_xor(part[0], 1);
        float t1 = part[1] + __shfl_xor(part[1], 1);
        float t2 = part[2] + __shfl_xor(part[2], 1);
        float t3 = part[3] + __shfl_xor(part[3], 1);
        float a0 = (gl & 1) ? t1 : t0;
        float a1 = (gl & 1) ? t3 : t2;
        a0 += __shfl_xor(a0, 2);
        a1 += __shfl_xor(a1, 2);
        float c = (gl & 2) ? a1 : a0;
        c += __shfl_xor(c, 4);

        const long long e = e0 + gl;
        if (gl < 4 && e < E) atomicAdd(&out[e], c + bias);
    }
}

extern "C" void kernel_launch(void* const* d_in, const int* in_sizes, int n_in,
                              void* d_out, int out_size, void* d_ws,
                              size_t ws_size, hipStream_t stream) {
    const float* tokens = (const float*)d_in[0];
    const float* coords = (const float*)d_in[1];
    const unsigned int* idxw = (const unsigned int*)d_in[2];
    const float* w1 = (const float*)d_in[3];
    const float* b1 = (const float*)d_in[4];
    const float* w2 = (const float*)d_in[5];
    const float* b2 = (const float*)d_in[6];
    float* out = (float*)d_out;

    const int N = in_sizes[0] / CH;       // 50000
    const int E = (int)(in_sizes[2] / 2); // 800000

    unsigned short* Plo = (unsigned short*)d_ws;   // [N][64] each
    unsigned short* Phi = Plo + (size_t)N * 64;
    unsigned short* Qlo = Phi + (size_t)N * 64;
    unsigned short* Qhi = Qlo + (size_t)N * 64;
    unsigned int* idxp = (unsigned int*)(Qhi + (size_t)N * 64);  // E u32
    unsigned short* Wf = (unsigned short*)(idxp + ((E + 3) & ~3));

    wf_prep<<<20, 256, 0, stream>>>(w1, b1, Wf);

    const int NB = (N + 31) / 32;
    node_fused<<<NB + 782 + 512, 256, 0, stream>>>(tokens, coords, Wf,
                                                   Plo, Phi, Qlo, Qhi, N, NB,
                                                   idxw, idxp, out, E);

    edge_fused<<<4096, 256, 0, stream>>>(idxp, Plo, Phi, Qlo, Qhi,
                                         w2, b2, out, (long long)E);
}